// Round 14
// baseline (267.549 us; speedup 1.0000x reference)
//
#include <hip/hip_runtime.h>

// SimpleNet R13: R11 exactly (direct per-value rcp — R12's shared-rcp
// regressed 164->183, falsifying the 16-cyc trans model; solved coefficients
// c_reg~4.7 / c_trans~9.4, both ~2.3x issue floors => wave-starved, not
// pipe-saturated) + __launch_bounds__(256, 6): force unified VGPR+AGPR
// total <= ~85/lane so 6 waves/SIMD can be resident (vs ~3 now; the unified
// AGPR accumulator allocation, invisible in VGPR_Count=56, was capping
// residency at ~168 regs/lane). One change; decisive occupancy experiment.
//
//   h = tanh(W_in[25x3] x); 6x: h = tanh(W[25x25] h); out = sigmoid(W_out[3x25] h)
// Layers as D[m][n] = A[m][k]*B[k][n], mfma_f32_16x16x32_f16, 2 M-tiles,
// 4 N-tiles (64 px/wave-iter), K=32. B operand carries r = rcp(exp2(a)+1);
// A' = -2*scale*W with bias column sum_c(W)*scale at k=7 (mu-row 19 = pad),
// B pad slot (j=7 / d1.w) packs constant 1.0. Input layer on MFMA (A_in
// cols 0..2; lanes q>=16 zero frags; packs (x0,x1),(x2,0),0,0 uniformly).
// A-frags staged in LDS (13.5 KiB), shared by the block's 4 waves.
//
// Relabeling: B element j of lane-group g = physical row mu(8g+j); physical
// rows carry logical channels via ch_map (pads at rows 19,23,27,28,29,30,31).
// Scales: hidden/input *2*log2e (r-domain tanh), output *-log2e (sigmoid=r).

#define HW_PIX (1024 * 1024)
#define NPIX   (4 * HW_PIX)
#define HID    25
#define DEPTH  6

#define TANH_SCALE 2.8853900817779268f    // 2*log2(e)
#define SIG_SCALE  (-1.4426950408889634f) // -log2(e)

typedef __fp16 h8 __attribute__((ext_vector_type(8)));
typedef __fp16 hpk2 __attribute__((ext_vector_type(2)));
typedef float f32x4 __attribute__((ext_vector_type(4)));

// ws layout (h8 units): [0,768) hidden A[(l*2+t)*64+q]; [768,832) A_out[q];
// [832,864) A_in[t*16+q] (2 tiles x 16 lanes; q>=16 lanes are zero frags).
#define WS_H8_TOTAL (13 * 64 + 32)

__device__ __forceinline__ int mu_map(int k) {
    int g = k >> 3, j = k & 7;
    return (j < 4) ? (4 * g + j) : (16 + 4 * g + (j & 3));
}

// physical row -> logical channel; -1 = pad.
__device__ __forceinline__ int ch_map(int m) {
    if (m <= 18) return m;
    if (m >= 20 && m <= 22) return m - 1;
    if (m >= 24 && m <= 26) return m - 2;
    return -1;
}

__global__ __launch_bounds__(256) void prep_kernel(
    const float* __restrict__ w_in, const float* __restrict__ ws,
    const float* __restrict__ w_out, __fp16* __restrict__ wsA)
{
    int tid = threadIdx.x;
    // hidden A-frags: 12 combos (layer l, tile t) x 64 lanes
    // A'[m,c] = -2*scale*W[m,c]; A'[m, k=7] = scale * sum_c W[m,c] (bias)
    for (int u = tid; u < 12 * 64; u += 256) {
        int q = u & 63, combo = u >> 6;
        int l = combo >> 1, t = combo & 1;
        int m = t * 16 + (q & 15);           // physical out row
        int cm = ch_map(m);                  // logical out channel
        for (int j = 0; j < 8; ++j) {
            int k = (q >> 4) * 8 + j;        // physical k column (0..31)
            float v = 0.0f;
            if (cm >= 0) {
                if (k == 7) {                // bias column (mu=19, pad row)
                    float s = 0.0f;
                    for (int c = 0; c < HID; ++c) s += ws[(l * HID + cm) * HID + c];
                    v = s * TANH_SCALE;
                } else {
                    int cc = ch_map(mu_map(k));
                    if (cc >= 0) v = -2.0f * TANH_SCALE * ws[(l * HID + cm) * HID + cc];
                }
            }
            wsA[u * 8 + j] = (__fp16)v;
        }
    }
    // output A-frag (rows 0..2 = out channels), same transform with SIG_SCALE
    if (tid < 64) {
        int q = tid, m = q & 15;
        for (int j = 0; j < 8; ++j) {
            int k = (q >> 4) * 8 + j;
            float v = 0.0f;
            if (m < 3) {
                if (k == 7) {
                    float s = 0.0f;
                    for (int c = 0; c < HID; ++c) s += w_out[m * HID + c];
                    v = s * SIG_SCALE;
                } else {
                    int cc = ch_map(mu_map(k));
                    if (cc >= 0) v = -2.0f * SIG_SCALE * w_out[m * HID + cc];
                }
            }
            wsA[(12 * 64 + q) * 8 + j] = (__fp16)v;
        }
    }
    // input A-frags: only lanes q<16 (k-base 0) nonzero; cols k=0..2 = input
    // channels, no bias. Row m = t*16+q carries logical channel ch_map(m).
    if (tid < 32) {
        int t = tid >> 4, q = tid & 15;
        int m = t * 16 + q;
        int cm = ch_map(m);
        for (int j = 0; j < 8; ++j) {
            float v = (cm >= 0 && j < 3) ? w_in[cm * 3 + j] * TANH_SCALE : 0.0f;
            wsA[(13 * 64 + t * 16 + q) * 8 + j] = (__fp16)v;
        }
    }
}

// r = rcp(exp2(a)+1): 2 trans + 1 add, 3-deep chain.
__device__ __forceinline__ float ract(float a) {
    return __builtin_amdgcn_rcpf(__builtin_amdgcn_exp2f(a) + 1.0f);
}

// activation + repack for one (d0,d1) MFMA pair; d1.w is the pad/bias slot.
__device__ __forceinline__ h8 act_pack(f32x4 d0, f32x4 d1) {
    union { h8 v; hpk2 p[4]; } u;
    u.p[0] = __builtin_amdgcn_cvt_pkrtz(ract(d0.x), ract(d0.y));
    u.p[1] = __builtin_amdgcn_cvt_pkrtz(ract(d0.z), ract(d0.w));
    u.p[2] = __builtin_amdgcn_cvt_pkrtz(ract(d1.x), ract(d1.y));
    u.p[3] = __builtin_amdgcn_cvt_pkrtz(ract(d1.z), 1.0f);  // bias slot
    return u.v;
}

__global__ __launch_bounds__(256, 6) void simplenet_kernel(
    const float* __restrict__ x,     // [4,3,1024,1024]
    const h8* __restrict__ wsA,      // packed A fragments (global)
    float* __restrict__ out)         // [4,3,1024,1024]
{
    __shared__ h8 sA[WS_H8_TOTAL];   // 13.5 KiB: shared by all 4 waves

    const int tid = threadIdx.x;
    const int lane = tid & 63;
    const int wgid = blockIdx.x * 4 + (tid >> 6);
    const int g = lane >> 4, col = lane & 15;

    // cooperative stage of all A fragments into LDS (one-time)
    for (int i = tid; i < WS_H8_TOTAL; i += 256) sA[i] = wsA[i];
    __syncthreads();

    // small frags stay in registers: Aout (4 regs) + Ain (8 regs)
    h8 zero8 = {};
    h8 Aout = sA[12 * 64 + lane];
    h8 Ain0 = (lane < 16) ? sA[13 * 64 + lane]      : zero8;
    h8 Ain1 = (lane < 16) ? sA[13 * 64 + 16 + lane] : zero8;

    const int pbase = wgid * 512;           // 512 consecutive pixels per wave
    const int b = pbase >> 20;              // image index (512 | 2^20: no straddle)
    const int hwb = pbase & (HW_PIX - 1);
    const float* xb = x + (size_t)b * 3 * HW_PIX;
    float* ob = out + (size_t)b * 3 * HW_PIX;

    for (int it = 0; it < 8; ++it) {
        const int hw0 = hwb + it * 64;

        // ---- input layer via MFMA: pack (x0,x1),(x2,0),0,0; A_in cols 0..2 ----
        h8 B[4];
#pragma unroll
        for (int n = 0; n < 4; ++n) {
            const int hw = hw0 + n * 16 + col;
            float x0 = xb[0 * HW_PIX + hw];
            float x1 = xb[1 * HW_PIX + hw];
            float x2 = xb[2 * HW_PIX + hw];
            union { h8 v; hpk2 p[4]; } ux;
            ux.p[0] = __builtin_amdgcn_cvt_pkrtz(x0, x1);
            ux.p[1] = __builtin_amdgcn_cvt_pkrtz(x2, 0.0f);
            ux.p[2] = hpk2{};
            ux.p[3] = hpk2{};
            f32x4 zc = {0.0f, 0.0f, 0.0f, 0.0f};
            f32x4 d0 = __builtin_amdgcn_mfma_f32_16x16x32_f16(Ain0, ux.v, zc, 0, 0, 0);
            f32x4 d1 = __builtin_amdgcn_mfma_f32_16x16x32_f16(Ain1, ux.v, zc, 0, 0, 0);
            B[n] = act_pack(d0, d1);
        }

        // ---- 6 hidden layers: A read from LDS (ds_read_b128, CSE'd over n) ----
#pragma unroll
        for (int l = 0; l < 6; ++l) {
            h8 a0 = sA[(l * 2 + 0) * 64 + lane];
            h8 a1 = sA[(l * 2 + 1) * 64 + lane];
#pragma unroll
            for (int n = 0; n < 4; ++n) {
                f32x4 zc = {0.0f, 0.0f, 0.0f, 0.0f};
                f32x4 d0 = __builtin_amdgcn_mfma_f32_16x16x32_f16(a0, B[n], zc, 0, 0, 0);
                f32x4 d1 = __builtin_amdgcn_mfma_f32_16x16x32_f16(a1, B[n], zc, 0, 0, 0);
                // D tile t reg r = phys row (t*16 + 4g + r); next B elem j:
                //   j<4 -> tile0 reg j ; j>=4 -> tile1 reg j-4.
                // d1.w = rows {19,23,27,31} = pad -> bias slot, pack 1.0.
                B[n] = act_pack(d0, d1);
            }
        }

        // ---- output layer: sigmoid == r; channels in rows 0..2 (g==0) ----
#pragma unroll
        for (int n = 0; n < 4; ++n) {
            f32x4 zc = {0.0f, 0.0f, 0.0f, 0.0f};
            f32x4 d = __builtin_amdgcn_mfma_f32_16x16x32_f16(Aout, B[n], zc, 0, 0, 0);
            if (g == 0) {
                const int hw = hw0 + n * 16 + col;
                ob[0 * HW_PIX + hw] = ract(d.x);
                ob[1 * HW_PIX + hw] = ract(d.y);
                ob[2 * HW_PIX + hw] = ract(d.z);
            }
        }
    }
}

extern "C" void kernel_launch(void* const* d_in, const int* in_sizes, int n_in,
                              void* d_out, int out_size, void* d_ws, size_t ws_size,
                              hipStream_t stream) {
    const float* x     = (const float*)d_in[0];
    const float* w_in  = (const float*)d_in[1];
    const float* ws    = (const float*)d_in[2];
    const float* w_out = (const float*)d_in[3];
    float* out         = (float*)d_out;

    __fp16* wsA = (__fp16*)d_ws;

    hipLaunchKernelGGL(prep_kernel, dim3(1), dim3(256), 0, stream,
                       w_in, ws, w_out, wsA);

    // 8192 waves x 8 iters x 64 px = 4Mi pixels, exact
    hipLaunchKernelGGL(simplenet_kernel, dim3(2048), dim3(256), 0, stream,
                       x, (const h8*)d_ws, out);
}

// Round 19
// 247.758 us; speedup vs baseline: 1.0799x; 1.0799x over previous
//
#include <hip/hip_runtime.h>

// SimpleNet R14: R11 math, NTILES=2 (32 px/iter, 16 iters) + launch_bounds
// (256,6). R13 taught: (256,6) with NTILES=4 spills (~180 MB/dispatch scratch,
// FETCH 24.7->144 MB) because B[4]+4 acc-pairs don't fit 85 regs; occupancy
// DID rise 37.5->50%, proving regs (unified VGPR+AGPR) are the residency cap.
// R9 proved intra-wave ILP is neutral at this occupancy, so NTILES=4 has no
// value extra waves can't replace. NTILES=2 working set ~70 regs -> 6
// waves/SIMD without spill; occupancy scaling (R10->R11: +25% occ = -11%
// time) should compress the stall-inflated cost coefficients.
//
//   h = tanh(W_in[25x3] x); 6x: h = tanh(W[25x25] h); out = sigmoid(W_out[3x25] h)
// Layers as D[m][n] = A[m][k]*B[k][n], mfma_f32_16x16x32_f16, 2 M-tiles,
// 2 N-tiles (32 px/wave-iter), K=32. B operand carries r = rcp(exp2(a)+1);
// A' = -2*scale*W with bias column sum_c(W)*scale at k=7 (mu-row 19 = pad),
// B pad slot (j=7 / d1.w) packs constant 1.0. Input layer on MFMA (A_in
// cols 0..2; lanes q>=16 zero frags; packs (x0,x1),(x2,0),0,0 uniformly).
// A-frags staged in LDS (13.5 KiB), shared by the block's 4 waves.
//
// Relabeling: B element j of lane-group g = physical row mu(8g+j); physical
// rows carry logical channels via ch_map (pads at rows 19,23,27,28,29,30,31).
// Scales: hidden/input *2*log2e (r-domain tanh), output *-log2e (sigmoid=r).

#define HW_PIX (1024 * 1024)
#define NPIX   (4 * HW_PIX)
#define HID    25
#define DEPTH  6

#define TANH_SCALE 2.8853900817779268f    // 2*log2(e)
#define SIG_SCALE  (-1.4426950408889634f) // -log2(e)

typedef __fp16 h8 __attribute__((ext_vector_type(8)));
typedef __fp16 hpk2 __attribute__((ext_vector_type(2)));
typedef float f32x4 __attribute__((ext_vector_type(4)));

// ws layout (h8 units): [0,768) hidden A[(l*2+t)*64+q]; [768,832) A_out[q];
// [832,864) A_in[t*16+q] (2 tiles x 16 lanes; q>=16 lanes are zero frags).
#define WS_H8_TOTAL (13 * 64 + 32)

__device__ __forceinline__ int mu_map(int k) {
    int g = k >> 3, j = k & 7;
    return (j < 4) ? (4 * g + j) : (16 + 4 * g + (j & 3));
}

// physical row -> logical channel; -1 = pad.
__device__ __forceinline__ int ch_map(int m) {
    if (m <= 18) return m;
    if (m >= 20 && m <= 22) return m - 1;
    if (m >= 24 && m <= 26) return m - 2;
    return -1;
}

__global__ __launch_bounds__(256) void prep_kernel(
    const float* __restrict__ w_in, const float* __restrict__ ws,
    const float* __restrict__ w_out, __fp16* __restrict__ wsA)
{
    int tid = threadIdx.x;
    // hidden A-frags: 12 combos (layer l, tile t) x 64 lanes
    // A'[m,c] = -2*scale*W[m,c]; A'[m, k=7] = scale * sum_c W[m,c] (bias)
    for (int u = tid; u < 12 * 64; u += 256) {
        int q = u & 63, combo = u >> 6;
        int l = combo >> 1, t = combo & 1;
        int m = t * 16 + (q & 15);           // physical out row
        int cm = ch_map(m);                  // logical out channel
        for (int j = 0; j < 8; ++j) {
            int k = (q >> 4) * 8 + j;        // physical k column (0..31)
            float v = 0.0f;
            if (cm >= 0) {
                if (k == 7) {                // bias column (mu=19, pad row)
                    float s = 0.0f;
                    for (int c = 0; c < HID; ++c) s += ws[(l * HID + cm) * HID + c];
                    v = s * TANH_SCALE;
                } else {
                    int cc = ch_map(mu_map(k));
                    if (cc >= 0) v = -2.0f * TANH_SCALE * ws[(l * HID + cm) * HID + cc];
                }
            }
            wsA[u * 8 + j] = (__fp16)v;
        }
    }
    // output A-frag (rows 0..2 = out channels), same transform with SIG_SCALE
    if (tid < 64) {
        int q = tid, m = q & 15;
        for (int j = 0; j < 8; ++j) {
            int k = (q >> 4) * 8 + j;
            float v = 0.0f;
            if (m < 3) {
                if (k == 7) {
                    float s = 0.0f;
                    for (int c = 0; c < HID; ++c) s += w_out[m * HID + c];
                    v = s * SIG_SCALE;
                } else {
                    int cc = ch_map(mu_map(k));
                    if (cc >= 0) v = -2.0f * SIG_SCALE * w_out[m * HID + cc];
                }
            }
            wsA[(12 * 64 + q) * 8 + j] = (__fp16)v;
        }
    }
    // input A-frags: only lanes q<16 (k-base 0) nonzero; cols k=0..2 = input
    // channels, no bias. Row m = t*16+q carries logical channel ch_map(m).
    if (tid < 32) {
        int t = tid >> 4, q = tid & 15;
        int m = t * 16 + q;
        int cm = ch_map(m);
        for (int j = 0; j < 8; ++j) {
            float v = (cm >= 0 && j < 3) ? w_in[cm * 3 + j] * TANH_SCALE : 0.0f;
            wsA[(13 * 64 + t * 16 + q) * 8 + j] = (__fp16)v;
        }
    }
}

// r = rcp(exp2(a)+1): 2 trans + 1 add, 3-deep chain.
__device__ __forceinline__ float ract(float a) {
    return __builtin_amdgcn_rcpf(__builtin_amdgcn_exp2f(a) + 1.0f);
}

// activation + repack for one (d0,d1) MFMA pair; d1.w is the pad/bias slot.
__device__ __forceinline__ h8 act_pack(f32x4 d0, f32x4 d1) {
    union { h8 v; hpk2 p[4]; } u;
    u.p[0] = __builtin_amdgcn_cvt_pkrtz(ract(d0.x), ract(d0.y));
    u.p[1] = __builtin_amdgcn_cvt_pkrtz(ract(d0.z), ract(d0.w));
    u.p[2] = __builtin_amdgcn_cvt_pkrtz(ract(d1.x), ract(d1.y));
    u.p[3] = __builtin_amdgcn_cvt_pkrtz(ract(d1.z), 1.0f);  // bias slot
    return u.v;
}

__global__ __launch_bounds__(256, 6) void simplenet_kernel(
    const float* __restrict__ x,     // [4,3,1024,1024]
    const h8* __restrict__ wsA,      // packed A fragments (global)
    float* __restrict__ out)         // [4,3,1024,1024]
{
    __shared__ h8 sA[WS_H8_TOTAL];   // 13.5 KiB: shared by all 4 waves

    const int tid = threadIdx.x;
    const int lane = tid & 63;
    const int wgid = blockIdx.x * 4 + (tid >> 6);
    const int g = lane >> 4, col = lane & 15;

    // cooperative stage of all A fragments into LDS (one-time)
    for (int i = tid; i < WS_H8_TOTAL; i += 256) sA[i] = wsA[i];
    __syncthreads();

    // small frags stay in registers: Aout (4 regs) + Ain (8 regs)
    h8 zero8 = {};
    h8 Aout = sA[12 * 64 + lane];
    h8 Ain0 = (lane < 16) ? sA[13 * 64 + lane]      : zero8;
    h8 Ain1 = (lane < 16) ? sA[13 * 64 + 16 + lane] : zero8;

    const int pbase = wgid * 512;           // 512 consecutive pixels per wave
    const int b = pbase >> 20;              // image index (512 | 2^20: no straddle)
    const int hwb = pbase & (HW_PIX - 1);
    const float* xb = x + (size_t)b * 3 * HW_PIX;
    float* ob = out + (size_t)b * 3 * HW_PIX;

    for (int it = 0; it < 16; ++it) {
        const int hw0 = hwb + it * 32;

        // ---- input layer via MFMA: pack (x0,x1),(x2,0),0,0; A_in cols 0..2 ----
        h8 B[2];
#pragma unroll
        for (int n = 0; n < 2; ++n) {
            const int hw = hw0 + n * 16 + col;
            float x0 = xb[0 * HW_PIX + hw];
            float x1 = xb[1 * HW_PIX + hw];
            float x2 = xb[2 * HW_PIX + hw];
            union { h8 v; hpk2 p[4]; } ux;
            ux.p[0] = __builtin_amdgcn_cvt_pkrtz(x0, x1);
            ux.p[1] = __builtin_amdgcn_cvt_pkrtz(x2, 0.0f);
            ux.p[2] = hpk2{};
            ux.p[3] = hpk2{};
            f32x4 zc = {0.0f, 0.0f, 0.0f, 0.0f};
            f32x4 d0 = __builtin_amdgcn_mfma_f32_16x16x32_f16(Ain0, ux.v, zc, 0, 0, 0);
            f32x4 d1 = __builtin_amdgcn_mfma_f32_16x16x32_f16(Ain1, ux.v, zc, 0, 0, 0);
            B[n] = act_pack(d0, d1);
        }

        // ---- 6 hidden layers: A read from LDS (ds_read_b128, CSE'd over n) ----
#pragma unroll
        for (int l = 0; l < 6; ++l) {
            h8 a0 = sA[(l * 2 + 0) * 64 + lane];
            h8 a1 = sA[(l * 2 + 1) * 64 + lane];
#pragma unroll
            for (int n = 0; n < 2; ++n) {
                f32x4 zc = {0.0f, 0.0f, 0.0f, 0.0f};
                f32x4 d0 = __builtin_amdgcn_mfma_f32_16x16x32_f16(a0, B[n], zc, 0, 0, 0);
                f32x4 d1 = __builtin_amdgcn_mfma_f32_16x16x32_f16(a1, B[n], zc, 0, 0, 0);
                // D tile t reg r = phys row (t*16 + 4g + r); next B elem j:
                //   j<4 -> tile0 reg j ; j>=4 -> tile1 reg j-4.
                // d1.w = rows {19,23,27,31} = pad -> bias slot, pack 1.0.
                B[n] = act_pack(d0, d1);
            }
        }

        // ---- output layer: sigmoid == r; channels in rows 0..2 (g==0) ----
#pragma unroll
        for (int n = 0; n < 2; ++n) {
            f32x4 zc = {0.0f, 0.0f, 0.0f, 0.0f};
            f32x4 d = __builtin_amdgcn_mfma_f32_16x16x32_f16(Aout, B[n], zc, 0, 0, 0);
            if (g == 0) {
                const int hw = hw0 + n * 16 + col;
                ob[0 * HW_PIX + hw] = ract(d.x);
                ob[1 * HW_PIX + hw] = ract(d.y);
                ob[2 * HW_PIX + hw] = ract(d.z);
            }
        }
    }
}

extern "C" void kernel_launch(void* const* d_in, const int* in_sizes, int n_in,
                              void* d_out, int out_size, void* d_ws, size_t ws_size,
                              hipStream_t stream) {
    const float* x     = (const float*)d_in[0];
    const float* w_in  = (const float*)d_in[1];
    const float* ws    = (const float*)d_in[2];
    const float* w_out = (const float*)d_in[3];
    float* out         = (float*)d_out;

    __fp16* wsA = (__fp16*)d_ws;

    hipLaunchKernelGGL(prep_kernel, dim3(1), dim3(256), 0, stream,
                       w_in, ws, w_out, wsA);

    // 8192 waves x 16 iters x 32 px = 4Mi pixels, exact
    hipLaunchKernelGGL(simplenet_kernel, dim3(2048), dim3(256), 0, stream,
                       x, (const h8*)d_ws, out);
}